// Round 14
// baseline (108.807 us; speedup 1.0000x reference)
//
#include <hip/hip_runtime.h>
#include <hip/hip_bf16.h>

#define B_    4
#define CIN   64
#define E_    75000
#define K_    5
#define COUT  128
#define KTOT  320   // K_*CIN
#define MROWS 64    // rows per block (4 waves x 16)
#define NBLK  1172  // ceil(E_/MROWS)

typedef __attribute__((ext_vector_type(8))) short short8;
typedef __attribute__((ext_vector_type(4))) float f32x4;
typedef __attribute__((ext_vector_type(4))) unsigned int u32x4;

typedef __attribute__((address_space(1))) const void gas_void;
typedef __attribute__((address_space(3))) void las_void;

static __device__ __forceinline__ unsigned short f2bf(float f) {
    __hip_bfloat16 h = __float2bfloat16(f);
    union { __hip_bfloat16 h; unsigned short u; } cv; cv.h = h; return cv.u;
}
static __device__ __forceinline__ float bflo(unsigned int v) { return __uint_as_float(v << 16); }
static __device__ __forceinline__ float bfhi(unsigned int v) { return __uint_as_float(v & 0xffff0000u); }
// packed f32->bf16 RNE (1 VALU inst)
static __device__ __forceinline__ unsigned int cvtpk(float lo, float hi) {
    unsigned int r;
    asm("v_cvt_pk_bf16_f32 %0, %1, %2" : "=v"(r) : "v"(lo), "v"(hi));
    return r;
}

// ---------------- Kernel 1: x (B,CIN,E) f32 -> f (B,E,CIN) bf16 ----------------
__global__ __launch_bounds__(256) void transpose_kernel(const float* __restrict__ x,
                                                        unsigned short* __restrict__ f) {
    __shared__ float lds[64][65];
    const int b  = blockIdx.y;
    const int e0 = blockIdx.x * 64;
    const int tid = threadIdx.x;
    const int lane_e = tid & 63;
    const int cg = tid >> 6;
    const int egc = min(e0 + lane_e, E_ - 1);
    const float* xb = x + (size_t)b * CIN * E_;
#pragma unroll
    for (int i = 0; i < 16; ++i) {
        int c = cg * 16 + i;
        lds[lane_e][c] = __builtin_nontemporal_load(&xb[(size_t)c * E_ + egc]);
    }
    __syncthreads();
    const int e = tid >> 2;
    const int q = tid & 3;
    if (e0 + e < E_) {
        unsigned short tmp[16] __attribute__((aligned(16)));
#pragma unroll
        for (int i = 0; i < 16; ++i) tmp[i] = f2bf(lds[e][q * 16 + i]);
        unsigned short* dst = f + ((size_t)b * E_ + e0 + e) * CIN + q * 16;
        *(short8*)dst       = *(short8*)&tmp[0];
        *(short8*)(dst + 8) = *(short8*)&tmp[8];
    }
}

// ------- Kernel 2: W -> fragment-ordered bf16 Wf, grouped by N-half -------
// dst frag index = ((ny*10 + s)*4 + nfh)*64 + lane, ny = nf>>2, nfh = nf&3 ;
// elem j = W[nf*16 + (lane&15)][s*32 + (lane>>4)*8 + j]
__global__ void wconv_kernel(const float* __restrict__ W, unsigned short* __restrict__ Wf) {
    int t = blockIdx.x * 256 + threadIdx.x;
    if (t >= 10 * 8 * 64) return;
    int lane = t & 63;
    int nf   = (t >> 6) & 7;
    int s    = t >> 9;
    int row = nf * 16 + (lane & 15);
    int col = s * 32 + (lane >> 4) * 8;
    const float* src = W + (size_t)row * KTOT + col;
    unsigned short tmp[8] __attribute__((aligned(16)));
#pragma unroll
    for (int j = 0; j < 8; ++j) tmp[j] = f2bf(src[j]);
    size_t dst = (((size_t)(nf >> 2) * 10 + s) * 4 + (nf & 3)) * 64 + lane;
    *(short8*)(Wf + dst * 8) = *(short8*)tmp;
}

// ------- Kernel 3: N-split gather-fused MFMA GEMM, half-Wf in LDS -------
// 256 threads = 4 waves x 16 rows; block covers 64 e-rows x 64 o-cols (ny half).
// LDS = 40 KB -> 4 independent barrier groups per CU anti-phase the pipeline.
// Wf half staged by global_load_lds DMA (no staging VGPRs).
static __device__ __forceinline__ short8 ldfrag(const unsigned short* __restrict__ base,
                                                unsigned int off_shorts) {
    return *(const short8*)(base + off_shorts);
}

static __device__ __forceinline__ void mk_sumdiff(short8 xa, short8 xb, short8& s8, short8& d8) {
    union U { short8 s; unsigned int u[4]; } ua, ub, us, ud;
    ua.s = xa; ub.s = xb;
#pragma unroll
    for (int i = 0; i < 4; ++i) {
        float al = bflo(ua.u[i]), ah = bfhi(ua.u[i]);
        float bl = bflo(ub.u[i]), bh = bfhi(ub.u[i]);
        us.u[i] = cvtpk(al + bl, ah + bh);
        ud.u[i] = cvtpk(al - bl, ah - bh) & 0x7fff7fffu;
    }
    s8 = us.s; d8 = ud.s;
}

__global__ __launch_bounds__(256)
__attribute__((amdgpu_waves_per_eu(4, 4)))
void meshconv_kernel(
    const unsigned short* __restrict__ f, const int* __restrict__ em,
    const unsigned short* __restrict__ Wf, const float* __restrict__ bias,
    float* __restrict__ out) {
    __shared__ u32x4 Bs[2560];                   // 40 KB: one N-half of Wf

    const int tid  = threadIdx.x;
    const int w    = tid >> 6, lane = tid & 63;
    const int ny   = blockIdx.y;                 // which 64-col output half
    const int b    = blockIdx.z;
    const int e0w  = blockIdx.x * MROWS + w * 16;
    const int l15  = lane & 15, l4 = lane >> 4;
    const int er   = min(e0w + l15, E_ - 1);     // this lane's source row (clamped tail)

    const unsigned short* fb = f + (size_t)b * E_ * CIN;

    // ---- DMA stage this half of Wf -> LDS (fire-and-forget, no VGPRs) ----
    {
        const u32x4* Wg = (const u32x4*)Wf + ny * 2560;
        const int wbase = tid & ~63;             // wave-uniform LDS slot base
#pragma unroll
        for (int i = 0; i < 10; ++i)
            __builtin_amdgcn_global_load_lds((gas_void*)(Wg + (i * 256 + tid)),
                                             (las_void*)(Bs + (i * 256 + wbase)), 16, 0, 0);
    }

    // ---- neighbor indices (k=0 is self by construction) ----
    const int* emr = em + ((size_t)b * E_ + er) * K_;
    int i1 = emr[1], i2 = emr[2], i3 = emr[3], i4 = emr[4];

    // ---- all 10 raw-fragment gathers in flight ----
    const unsigned int co = (unsigned int)(l4 * 8);
    short8 gS0 = ldfrag(fb, ((unsigned int)er << 6) + co);
    short8 gS1 = ldfrag(fb, ((unsigned int)er << 6) + 32 + co);
    short8 g1a = ldfrag(fb, ((unsigned int)i1 << 6) + co);
    short8 g1b = ldfrag(fb, ((unsigned int)i1 << 6) + 32 + co);
    short8 g2a = ldfrag(fb, ((unsigned int)i2 << 6) + co);
    short8 g2b = ldfrag(fb, ((unsigned int)i2 << 6) + 32 + co);
    short8 g3a = ldfrag(fb, ((unsigned int)i3 << 6) + co);
    short8 g3b = ldfrag(fb, ((unsigned int)i3 << 6) + 32 + co);
    short8 g4a = ldfrag(fb, ((unsigned int)i4 << 6) + co);
    short8 g4b = ldfrag(fb, ((unsigned int)i4 << 6) + 32 + co);

    __syncthreads();                              // staging DMA + gathers drained

    // ---- composite A fragments ----
    short8 A[10];
    A[0] = gS0; A[1] = gS1;
    mk_sumdiff(g1a, g3a, A[2], A[6]);
    mk_sumdiff(g1b, g3b, A[3], A[7]);
    mk_sumdiff(g2a, g4a, A[4], A[8]);
    mk_sumdiff(g2b, g4b, A[5], A[9]);

    // ---- acc init = bias for o = ny*64 + nf*16 + l15 ----
    f32x4 acc[4];
#pragma unroll
    for (int nf = 0; nf < 4; ++nf) {
        float bv = bias[ny * 64 + nf * 16 + l15];
        acc[nf] = (f32x4){bv, bv, bv, bv};
    }

    // ---- GEMM: 10 K-steps x 4 N-frags, B from LDS ----
    const short8* Bl = (const short8*)Bs;
#pragma unroll
    for (int s = 0; s < 10; ++s) {
#pragma unroll
        for (int nf = 0; nf < 4; ++nf) {
            short8 bfr = Bl[(s * 4 + nf) * 64 + lane];
            acc[nf] = __builtin_amdgcn_mfma_f32_16x16x32_bf16(A[s], bfr, acc[nf], 0, 0, 0);
        }
    }

    // ---- epilogue: store; out (B, COUT, E). E%4==0 -> aligned f32x4 ----
    float* ob = out + (size_t)b * COUT * E_;
    const int erow = e0w + l4 * 4;
    if (erow < E_) {
#pragma unroll
        for (int nf = 0; nf < 4; ++nf) {
            int o = ny * 64 + nf * 16 + l15;
            *(f32x4*)(ob + (size_t)o * E_ + erow) = acc[nf];
        }
    }
}

extern "C" void kernel_launch(void* const* d_in, const int* in_sizes, int n_in,
                              void* d_out, int out_size, void* d_ws, size_t ws_size,
                              hipStream_t stream) {
    const float* x    = (const float*)d_in[0];
    const int*   em   = (const int*)d_in[1];
    const float* W    = (const float*)d_in[2];
    const float* bias = (const float*)d_in[3];
    float* out = (float*)d_out;

    unsigned short* f  = (unsigned short*)d_ws;                 // B*E*64 bf16 = 38.4 MB
    unsigned short* Wf = f + (size_t)B_ * E_ * CIN;             // 80 KB fragment-ordered W

    dim3 gridT(1172, B_);
    transpose_kernel<<<gridT, 256, 0, stream>>>(x, f);
    wconv_kernel<<<20, 256, 0, stream>>>(W, Wf);
    dim3 gridM(NBLK, 2, B_);
    meshconv_kernel<<<gridM, 256, 0, stream>>>(f, em, Wf, bias, out);
}

// Round 15
// 94.607 us; speedup vs baseline: 1.1501x; 1.1501x over previous
//
#include <hip/hip_runtime.h>
#include <hip/hip_bf16.h>

#define B_    4
#define CIN   64
#define E_    75000
#define K_    5
#define COUT  128
#define KTOT  320   // K_*CIN
#define MROWS 128   // rows per block (4 waves x 32)
#define NBLK  586   // ceil(E_/MROWS)

typedef __attribute__((ext_vector_type(8))) short short8;
typedef __attribute__((ext_vector_type(4))) float f32x4;
typedef __attribute__((ext_vector_type(16))) float f32x16;
typedef __attribute__((ext_vector_type(4))) unsigned int u32x4;

typedef __attribute__((address_space(1))) const void gas_void;
typedef __attribute__((address_space(3))) void las_void;

static __device__ __forceinline__ unsigned short f2bf(float f) {
    __hip_bfloat16 h = __float2bfloat16(f);
    union { __hip_bfloat16 h; unsigned short u; } cv; cv.h = h; return cv.u;
}
static __device__ __forceinline__ float bflo(unsigned int v) { return __uint_as_float(v << 16); }
static __device__ __forceinline__ float bfhi(unsigned int v) { return __uint_as_float(v & 0xffff0000u); }
// packed f32->bf16 RNE (1 VALU inst)
static __device__ __forceinline__ unsigned int cvtpk(float lo, float hi) {
    unsigned int r;
    asm("v_cvt_pk_bf16_f32 %0, %1, %2" : "=v"(r) : "v"(lo), "v"(hi));
    return r;
}

// ---------------- Kernel 1: x (B,CIN,E) f32 -> f (B,E,CIN) bf16 ----------------
__global__ __launch_bounds__(256) void transpose_kernel(const float* __restrict__ x,
                                                        unsigned short* __restrict__ f) {
    __shared__ float lds[64][65];
    const int b  = blockIdx.y;
    const int e0 = blockIdx.x * 64;
    const int tid = threadIdx.x;
    const int lane_e = tid & 63;
    const int cg = tid >> 6;
    const int egc = min(e0 + lane_e, E_ - 1);
    const float* xb = x + (size_t)b * CIN * E_;
#pragma unroll
    for (int i = 0; i < 16; ++i) {
        int c = cg * 16 + i;
        lds[lane_e][c] = __builtin_nontemporal_load(&xb[(size_t)c * E_ + egc]);
    }
    __syncthreads();
    const int e = tid >> 2;
    const int q = tid & 3;
    if (e0 + e < E_) {
        unsigned short tmp[16] __attribute__((aligned(16)));
#pragma unroll
        for (int i = 0; i < 16; ++i) tmp[i] = f2bf(lds[e][q * 16 + i]);
        unsigned short* dst = f + ((size_t)b * E_ + e0 + e) * CIN + q * 16;
        *(short8*)dst       = *(short8*)&tmp[0];
        *(short8*)(dst + 8) = *(short8*)&tmp[8];
    }
}

// ------- Kernel 2: W (COUT,KTOT) f32 -> 32x32x16-fragment-ordered bf16 Wf -------
// frag t = (S*4 + nf)*64 + lane, S = g*4 + s (20 global K-steps, groups g=feature
// block 0..4). elem j = W[nf*32 + (lane&31)][g*64 + (lane>>5)*32 + s*8 + j]
// (K-channels permuted within each 64-group so a lane's A-half is contiguous.)
__global__ void wconv_kernel(const float* __restrict__ W, unsigned short* __restrict__ Wf) {
    int t = blockIdx.x * 256 + threadIdx.x;
    if (t >= 20 * 4 * 64) return;
    int lane = t & 63;
    int nf   = (t >> 6) & 3;
    int S    = t >> 8;              // 0..19
    int g = S >> 2, s = S & 3;
    int row = nf * 32 + (lane & 31);
    int col = g * 64 + (lane >> 5) * 32 + s * 8;
    const float* src = W + (size_t)row * KTOT + col;
    unsigned short tmp[8] __attribute__((aligned(16)));
#pragma unroll
    for (int j = 0; j < 8; ++j) tmp[j] = f2bf(src[j]);
    *(short8*)(Wf + (size_t)t * 8) = *(short8*)tmp;
}

// ------- Kernel 3: gather-fused 32x32x16 MFMA GEMM, B in LDS -------
// 256 threads = 4 waves x 32 rows. Each ds_read_b128 B-frag feeds 32 output
// rows (2x R8) -> LDS traffic and MFMA count per row halve. 80 KB LDS ->
// 2 blocks/CU = 2 waves/EU -> 256-VGPR tier (pinned): the 20 gathers +
// composites + 64-reg acc all stay in registers, un-serializable.
static __device__ __forceinline__ short8 ldfrag(const unsigned short* __restrict__ base,
                                                unsigned int off_shorts) {
    return *(const short8*)(base + off_shorts);
}

static __device__ __forceinline__ void mk_sumdiff(short8 xa, short8 xb, short8& s8, short8& d8) {
    union U { short8 s; unsigned int u[4]; } ua, ub, us, ud;
    ua.s = xa; ub.s = xb;
#pragma unroll
    for (int i = 0; i < 4; ++i) {
        float al = bflo(ua.u[i]), ah = bfhi(ua.u[i]);
        float bl = bflo(ub.u[i]), bh = bfhi(ub.u[i]);
        us.u[i] = cvtpk(al + bl, ah + bh);
        ud.u[i] = cvtpk(al - bl, ah - bh) & 0x7fff7fffu;
    }
    s8 = us.s; d8 = ud.s;
}

__global__ __launch_bounds__(256)
__attribute__((amdgpu_waves_per_eu(2, 2)))
void meshconv_kernel(
    const unsigned short* __restrict__ f, const int* __restrict__ em,
    const unsigned short* __restrict__ Wf, const float* __restrict__ bias,
    float* __restrict__ out) {
    __shared__ u32x4 Bs[5120];                   // 80 KB: all of Wf

    const int tid  = threadIdx.x;
    const int w    = tid >> 6, lane = tid & 63;
    const int b    = blockIdx.y;
    const int l31  = lane & 31, ksub = lane >> 5;
    const int e0w  = blockIdx.x * MROWS + w * 32;
    const int er   = min(e0w + l31, E_ - 1);     // this lane's e-row (clamped tail)

    const unsigned short* fb = f + (size_t)b * E_ * CIN;

    // ---- DMA stage Wf -> LDS (20 x 16B per thread, zero staging VGPRs) ----
    {
        const u32x4* Wg = (const u32x4*)Wf;
        const int wbase = tid & ~63;             // wave-uniform LDS slot base
#pragma unroll
        for (int i = 0; i < 20; ++i)
            __builtin_amdgcn_global_load_lds((gas_void*)(Wg + (i * 256 + tid)),
                                             (las_void*)(Bs + (i * 256 + wbase)), 16, 0, 0);
    }

    // ---- neighbor indices (k=0 is self by construction) ----
    const int* emr = em + ((size_t)b * E_ + er) * K_;
    int i1 = emr[1], i2 = emr[2], i3 = emr[3], i4 = emr[4];

    // ---- 20 raw gathers: lane covers channels [ksub*32, ksub*32+32) of 5 rows ----
    const unsigned int co = (unsigned int)(ksub * 32);   // shorts
    short8 gS[4], g1[4], g2[4], g3[4], g4[4];
    {
        unsigned int r0 = (unsigned int)er << 6;
        unsigned int r1 = (unsigned int)i1 << 6, r2 = (unsigned int)i2 << 6;
        unsigned int r3 = (unsigned int)i3 << 6, r4 = (unsigned int)i4 << 6;
#pragma unroll
        for (int q = 0; q < 4; ++q) {
            gS[q] = ldfrag(fb, r0 + co + q * 8);
            g1[q] = ldfrag(fb, r1 + co + q * 8);
            g2[q] = ldfrag(fb, r2 + co + q * 8);
            g3[q] = ldfrag(fb, r3 + co + q * 8);
            g4[q] = ldfrag(fb, r4 + co + q * 8);
        }
    }

    __syncthreads();                              // staging DMA + gathers drained

    // ---- composite A fragments: groups [self, s13, s24, d13, d24] ----
    short8 A[20];
#pragma unroll
    for (int q = 0; q < 4; ++q) {
        A[q] = gS[q];
        mk_sumdiff(g1[q], g3[q], A[4 + q], A[12 + q]);
        mk_sumdiff(g2[q], g4[q], A[8 + q], A[16 + q]);
    }

    // ---- acc init = bias; o = nf*32 + l31 ----
    f32x16 acc[4];
#pragma unroll
    for (int nf = 0; nf < 4; ++nf) {
        float bv = bias[nf * 32 + l31];
#pragma unroll
        for (int j = 0; j < 16; ++j) acc[nf][j] = bv;
    }

    // ---- GEMM: 20 K-steps x 4 N-frags of 32x32x16 ----
    const short8* Bl = (const short8*)Bs;
#pragma unroll
    for (int S = 0; S < 20; ++S) {
#pragma unroll
        for (int nf = 0; nf < 4; ++nf) {
            short8 bfr = Bl[(S * 4 + nf) * 64 + lane];
            acc[nf] = __builtin_amdgcn_mfma_f32_32x32x16_bf16(A[S], bfr, acc[nf], 0, 0, 0);
        }
    }

    // ---- epilogue: C/D layout col=l31, row=(r&3)+8*(r>>2)+4*ksub ----
    float* ob = out + (size_t)b * COUT * E_;
#pragma unroll
    for (int nf = 0; nf < 4; ++nf) {
        const int o = nf * 32 + l31;
        float* obo = ob + (size_t)o * E_;
#pragma unroll
        for (int rr = 0; rr < 4; ++rr) {
            int ebase = e0w + 8 * rr + 4 * ksub;
            if (ebase < E_) {                     // 4-row groups never straddle E_
                f32x4 v = {acc[nf][rr * 4 + 0], acc[nf][rr * 4 + 1],
                           acc[nf][rr * 4 + 2], acc[nf][rr * 4 + 3]};
                *(f32x4*)(obo + ebase) = v;
            }
        }
    }
}

extern "C" void kernel_launch(void* const* d_in, const int* in_sizes, int n_in,
                              void* d_out, int out_size, void* d_ws, size_t ws_size,
                              hipStream_t stream) {
    const float* x    = (const float*)d_in[0];
    const int*   em   = (const int*)d_in[1];
    const float* W    = (const float*)d_in[2];
    const float* bias = (const float*)d_in[3];
    float* out = (float*)d_out;

    unsigned short* f  = (unsigned short*)d_ws;                 // B*E*64 bf16 = 38.4 MB
    unsigned short* Wf = f + (size_t)B_ * E_ * CIN;             // 80 KB fragment-ordered W

    dim3 gridT(1172, B_);
    transpose_kernel<<<gridT, 256, 0, stream>>>(x, f);
    wconv_kernel<<<20, 256, 0, stream>>>(W, Wf);
    dim3 gridM(NBLK, B_);
    meshconv_kernel<<<gridM, 256, 0, stream>>>(f, em, Wf, bias, out);
}